// Round 15
// baseline (144.930 us; speedup 1.0000x reference)
//
#include <hip/hip_runtime.h>
#include <math.h>

#define LMAX  32768
#define WWIN  1024
#define KFIR  128
#define WOUT  512                // outputs per wave (two 256-output MFMA chunks)
#define TO    1024               // outputs per block (2 waves)
#define CPAD  656                // padded shift-copy length (halves); 1312 B (16B mult)
#define NMAX  1024               // max notes
#define PMAX  96                 // params chunk (LDS-resident note params)

typedef _Float16 v8h __attribute__((ext_vector_type(8)));
typedef _Float16 v4h __attribute__((ext_vector_type(4)));
typedef float    v4f __attribute__((ext_vector_type(4)));

__device__ __forceinline__ float fast_tanh(float x) {
    float e = __builtin_amdgcn_exp2f(x * 2.8853900817779268f);  // 2*log2(e)
    return fmaf(-2.0f, __builtin_amdgcn_rcpf(e + 1.0f), 1.0f);
}

// ---------------- single fused kernel ----------------
// r12's best synth structure (TO=1024, 2 waves x WOUT=512, fp16 4-shift-copy
// staging, 24x mfma_f32_16x16x32_f16 FIR) + in-block param MLP: each block
// stages the 970 MLP weights to LDS (L2-resident after first blocks) and
// computes params for its own note list (threads t<K, one note each) --
// removes the separate params_k dispatch entirely (total-synth gap probe).
__global__ __launch_bounds__(128, 3) void synth_fused_k(
    const float* __restrict__ freq_g, const float* __restrict__ velo_g,
    const float* __restrict__ w1,  const float* __restrict__ b1,
    const float* __restrict__ w2,  const float* __restrict__ b2,
    const float* __restrict__ ws1, const float* __restrict__ bs1,
    const float* __restrict__ ws2, const float* __restrict__ bs2,
    const float* __restrict__ fir,
    const int* __restrict__ starts, const int* __restrict__ lengths,
    float* __restrict__ out, int Dn, int N)
{
    __shared__ __align__(16) _Float16 segc[2][4][CPAD];   // 10.5 KB
    __shared__ float fir_s[KFIR];
    __shared__ unsigned short note_list[NMAX];
    __shared__ int note_cnt;
    // MLP weights (staged once per block)
    __shared__ float s_w1[32], s_b1[32], s_w2[64], s_b2[2];
    __shared__ float s_ws1[256], s_bs1[64], s_ws2[512], s_bs2[8];
    // per-chunk note params
    __shared__ int   stl[PMAX], oll[PMAX];
    __shared__ float fl[PMAX];
    __shared__ __align__(16) float ampsl[PMAX][8];

    const int tid  = threadIdx.x;
    const int wid  = tid >> 6;
    const int lane = tid & 63;
    const int m    = lane & 15;
    const int quad = lane >> 4;
    const int o0   = blockIdx.x * TO;
    const int o_end = min(o0 + TO, Dn);
    const int ow   = o0 + wid * WOUT;         // this wave's first output

    // ---- stage FIR taps + MLP weights ----
    fir_s[tid] = fir[tid];
    if (tid < 32) { s_w1[tid] = w1[tid]; s_b1[tid] = b1[tid]; }
    if (tid < 64) { s_w2[tid] = w2[tid]; s_bs1[tid] = bs1[tid]; }
    if (tid < 2)  s_b2[tid] = b2[tid];
    if (tid < 8)  s_bs2[tid] = bs2[tid];
    s_ws1[tid] = ws1[tid];       s_ws1[tid + 128] = ws1[tid + 128];
    s_ws2[tid] = ws2[tid];       s_ws2[tid + 128] = ws2[tid + 128];
    s_ws2[tid + 256] = ws2[tid + 256]; s_ws2[tid + 384] = ws2[tid + 384];
    if (tid == 0) note_cnt = 0;
    __syncthreads();

    // ---- build note list for this tile ----
    for (int j = tid; j < N; j += 128) {
        int st = starts[j];
        int len = lengths[j];
        int ol = min(st + len, Dn) - st;
        ol = max(0, min(ol, LMAX));
        if (st < o_end && st + ol > o0) {
            int p = atomicAdd(&note_cnt, 1);
            note_list[p] = (unsigned short)j;
        }
    }
    __syncthreads();
    const int K = note_cnt;

    // ---- A fragments: shifted filter bank (constant for whole kernel) ----
    v8h afrag[12];
    #pragma unroll
    for (int t = 0; t < 12; ++t) {
        v8h af;
        #pragma unroll
        for (int j = 0; j < 8; ++j) {
            int idx = 32 * t + 8 * quad + j - 16 * m;
            float fv = (idx >= 0 && idx < KFIR) ? fir_s[idx] : 0.0f;
            af[j] = (_Float16)fv;
        }
        afrag[t] = af;
    }

    // ---- zero pad tails [636,656) of this wave's shift-copies ----
    for (int z = lane; z < 4 * 20; z += 64) {
        int S = z / 20, off = z % 20;
        segc[wid][S][636 + off] = (_Float16)0.0f;
    }

    // per-lane B read base: copy c = m&3, in-copy half index (m&~3)+8*quad (8B aligned)
    const _Float16* __restrict__ bbase = &segc[wid][m & 3][(m & ~3) + 8 * quad];

    float accA0 = 0.f, accA1 = 0.f, accA2 = 0.f, accA3 = 0.f;
    float accB0 = 0.f, accB1 = 0.f, accB2 = 0.f, accB3 = 0.f;

    const double inv2pi = 0.15915494309189535;

    for (int c = 0; c < K; c += PMAX) {
        const int kn = min(K - c, PMAX);

        // ---- compute this chunk's note params (thread t -> note_list[c+t]) ----
        __syncthreads();                      // protect params LDS from prior chunk
        if (tid < kn) {
            const int nid = (int)note_list[c + tid];
            int st  = starts[nid];
            int len = lengths[nid];
            int ol  = min(st + len, Dn) - st;
            ol = max(0, min(ol, LMAX));
            stl[tid] = st;
            oll[tid] = ol;
            float v = velo_g[nid] * (1.0f / 127.0f);
            float f = freq_g[nid];
            fl[tid] = f;
            float nt = (float)st / (float)Dn;
            float lat0 = s_b2[0], lat1 = s_b2[1];
            #pragma unroll
            for (int j = 0; j < 32; ++j) {
                float h = fmaxf(fmaf(nt, s_w1[j], s_b1[j]), 0.0f);
                lat0 = fmaf(h, s_w2[j * 2 + 0], lat0);
                lat1 = fmaf(h, s_w2[j * 2 + 1], lat1);
            }
            float acc[8];
            #pragma unroll
            for (int h = 0; h < 8; ++h) acc[h] = s_bs2[h];
            #pragma unroll
            for (int j = 0; j < 64; ++j) {
                float a = s_bs1[j];
                a = fmaf(f,    s_ws1[0 * 64 + j], a);
                a = fmaf(v,    s_ws1[1 * 64 + j], a);
                a = fmaf(lat0, s_ws1[2 * 64 + j], a);
                a = fmaf(lat1, s_ws1[3 * 64 + j], a);
                a = fmaxf(a, 0.0f);
                #pragma unroll
                for (int h = 0; h < 8; ++h)
                    acc[h] = fmaf(a, s_ws2[j * 8 + h], acc[h]);
            }
            #pragma unroll
            for (int h = 0; h < 8; ++h) {
                float a = acc[h];
                float sp = fmaxf(a, 0.0f) + log1pf(expf(-fabsf(a)));
                ampsl[tid][h] = sp * v;       // velocity folded in
            }
        }
        __syncthreads();

        // ---- pair loop over this chunk (no barriers inside) ----
        for (int kk = 0; kk < kn; ++kk) {
            const int st = stl[kk];
            const int ol = oll[kk];
            const int base = ow - st;         // note-local index of wave's first output
            if (base >= ol || base + WOUT <= 0) continue;   // wave-uniform skip

            const float f = fl[kk];
            const float4 am0 = *(const float4*)&ampsl[kk][0];
            const float4 am1 = *(const float4*)&ampsl[kk][4];
            const float A0 = am0.x, A1 = am0.y, A2 = am0.z, A3 = am0.w;
            const float A4 = am1.x, A5 = am1.y, A6 = am1.z, A7 = am1.w;
            const double fd = (double)f;

            // phase seed (f64 once per pair) + fixed-angle rotation stepping
            const int tseed = base - 127 + lane;
            double rev0 = fd * (double)tseed * inv2pi;
            float r0 = (float)(rev0 - floor(rev0));
            float s = __builtin_amdgcn_sinf(r0);
            float cc = __builtin_amdgcn_cosf(r0);
            double d64 = fd * 64.0 * inv2pi;
            float r64 = (float)(d64 - floor(d64));
            const float sd = __builtin_amdgcn_sinf(r64);
            const float cd = __builtin_amdgcn_cosf(r64);
            const int wbase = ol - WWIN;

            // wave-uniform fast path: no bounds checks, no Hann window
            const bool interior = (base >= 127) && (base + 513 <= wbase);

            if (interior) {
                #pragma unroll
                for (int i = 0; i < 10; ++i) {
                    float tc = cc + cc;
                    float sA = s;
                    float sum = A0 * sA;
                    float sB = tc * sA;              sum = fmaf(A1, sB, sum);
                    float sC = fmaf(tc, sB, -sA);    sum = fmaf(A2, sC, sum);
                    float sD = fmaf(tc, sC, -sB);    sum = fmaf(A3, sD, sum);
                    float sE = fmaf(tc, sD, -sC);    sum = fmaf(A4, sE, sum);
                    float sF = fmaf(tc, sE, -sD);    sum = fmaf(A5, sF, sum);
                    float sG = fmaf(tc, sF, -sE);    sum = fmaf(A6, sG, sum);
                    float sH = fmaf(tc, sG, -sF);    sum = fmaf(A7, sH, sum);
                    _Float16 h = (_Float16)sum;
                    const int x = lane + 64 * i;
                    if (i == 0) {
                        #pragma unroll
                        for (int S = 0; S < 4; ++S)
                            if (x >= S) segc[wid][S][x - S] = h;
                    } else {
                        #pragma unroll
                        for (int S = 0; S < 4; ++S)
                            segc[wid][S][x - S] = h;
                    }
                    float ns = fmaf(s, cd, cc * sd);
                    float nc = fmaf(cc, cd, -(s * sd));
                    s = ns; cc = nc;
                }
            } else {
                #pragma unroll
                for (int i = 0; i < 10; ++i) {
                    int t = tseed + 64 * i;
                    float val = 0.0f;
                    if (t >= 0 && t < ol) {
                        float tc = cc + cc;
                        float sA = s;
                        float sum = A0 * sA;
                        float sB = tc * sA;              sum = fmaf(A1, sB, sum);
                        float sC = fmaf(tc, sB, -sA);    sum = fmaf(A2, sC, sum);
                        float sD = fmaf(tc, sC, -sB);    sum = fmaf(A3, sD, sum);
                        float sE = fmaf(tc, sD, -sC);    sum = fmaf(A4, sE, sum);
                        float sF = fmaf(tc, sE, -sD);    sum = fmaf(A5, sF, sum);
                        float sG = fmaf(tc, sF, -sE);    sum = fmaf(A6, sG, sum);
                        float sH = fmaf(tc, sG, -sF);    sum = fmaf(A7, sH, sum);
                        int wpos = t - wbase;
                        float factor = 1.0f;
                        if (wpos >= 0)
                            factor = 0.5f - 0.5f * __builtin_amdgcn_cosf((float)wpos * (1.0f / WWIN));
                        val = sum * factor;
                    }
                    _Float16 h = (_Float16)val;
                    const int x = lane + 64 * i;
                    if (i == 0) {
                        #pragma unroll
                        for (int S = 0; S < 4; ++S)
                            if (x >= S) segc[wid][S][x - S] = h;
                    } else {
                        #pragma unroll
                        for (int S = 0; S < 4; ++S)
                            segc[wid][S][x - S] = h;
                    }
                    float ns = fmaf(s, cd, cc * sd);
                    float nc = fmaf(cc, cd, -(s * sd));
                    s = ns; cc = nc;
                }
            }

            // ---- FIR as 24x MFMA, 4 independent accumulator chains ----
            v4f CA0 = {0.f, 0.f, 0.f, 0.f};
            v4f CA1 = {0.f, 0.f, 0.f, 0.f};
            v4f CB0 = {0.f, 0.f, 0.f, 0.f};
            v4f CB1 = {0.f, 0.f, 0.f, 0.f};
            #pragma unroll
            for (int t = 0; t < 6; ++t) {
                v4h lo = *(const v4h*)(bbase + 32 * t);
                v4h hi = *(const v4h*)(bbase + 32 * t + 4);
                v8h bf = __builtin_shufflevector(lo, hi, 0, 1, 2, 3, 4, 5, 6, 7);
                CA0 = __builtin_amdgcn_mfma_f32_16x16x32_f16(afrag[t], bf, CA0, 0, 0, 0);
                v4h lo2 = *(const v4h*)(bbase + 256 + 32 * t);
                v4h hi2 = *(const v4h*)(bbase + 256 + 32 * t + 4);
                v8h bf2 = __builtin_shufflevector(lo2, hi2, 0, 1, 2, 3, 4, 5, 6, 7);
                CB0 = __builtin_amdgcn_mfma_f32_16x16x32_f16(afrag[t], bf2, CB0, 0, 0, 0);
            }
            #pragma unroll
            for (int t = 6; t < 12; ++t) {
                v4h lo = *(const v4h*)(bbase + 32 * t);
                v4h hi = *(const v4h*)(bbase + 32 * t + 4);
                v8h bf = __builtin_shufflevector(lo, hi, 0, 1, 2, 3, 4, 5, 6, 7);
                CA1 = __builtin_amdgcn_mfma_f32_16x16x32_f16(afrag[t], bf, CA1, 0, 0, 0);
                v4h lo2 = *(const v4h*)(bbase + 256 + 32 * t);
                v4h hi2 = *(const v4h*)(bbase + 256 + 32 * t + 4);
                v8h bf2 = __builtin_shufflevector(lo2, hi2, 0, 1, 2, 3, 4, 5, 6, 7);
                CB1 = __builtin_amdgcn_mfma_f32_16x16x32_f16(afrag[t], bf2, CB1, 0, 0, 0);
            }

            // ---- tanh + masked accumulate; chunkA p = 64q+16r+m, chunkB p+256 ----
            {
                const int tb = base + 64 * quad + m;
                float y;
                y = CA0[0] + CA1[0]; if (tb +   0 >= 0 && tb +   0 < ol) accA0 += fast_tanh(y);
                y = CA0[1] + CA1[1]; if (tb +  16 >= 0 && tb +  16 < ol) accA1 += fast_tanh(y);
                y = CA0[2] + CA1[2]; if (tb +  32 >= 0 && tb +  32 < ol) accA2 += fast_tanh(y);
                y = CA0[3] + CA1[3]; if (tb +  48 >= 0 && tb +  48 < ol) accA3 += fast_tanh(y);
                y = CB0[0] + CB1[0]; if (tb + 256 >= 0 && tb + 256 < ol) accB0 += fast_tanh(y);
                y = CB0[1] + CB1[1]; if (tb + 272 >= 0 && tb + 272 < ol) accB1 += fast_tanh(y);
                y = CB0[2] + CB1[2]; if (tb + 288 >= 0 && tb + 288 < ol) accB2 += fast_tanh(y);
                y = CB0[3] + CB1[3]; if (tb + 304 >= 0 && tb + 304 < ol) accB3 += fast_tanh(y);
            }
        }
    }

    // ---- stores (C/D layout: 16-lane coalesced runs) ----
    const int ob = ow + 64 * quad + m;
    if (ob +   0 < Dn) out[ob +   0] = accA0;
    if (ob +  16 < Dn) out[ob +  16] = accA1;
    if (ob +  32 < Dn) out[ob +  32] = accA2;
    if (ob +  48 < Dn) out[ob +  48] = accA3;
    if (ob + 256 < Dn) out[ob + 256] = accB0;
    if (ob + 272 < Dn) out[ob + 272] = accB1;
    if (ob + 288 < Dn) out[ob + 288] = accB2;
    if (ob + 304 < Dn) out[ob + 304] = accB3;
}

// ---------------- launcher (single dispatch) ----------------
extern "C" void kernel_launch(void* const* d_in, const int* in_sizes, int n_in,
                              void* d_out, int out_size, void* d_ws, size_t ws_size,
                              hipStream_t stream) {
    const float* freq    = (const float*)d_in[0];
    const float* velo    = (const float*)d_in[1];
    const float* w1      = (const float*)d_in[2];
    const float* b1      = (const float*)d_in[3];
    const float* w2      = (const float*)d_in[4];
    const float* b2      = (const float*)d_in[5];
    const float* ws1     = (const float*)d_in[6];
    const float* bs1     = (const float*)d_in[7];
    const float* ws2     = (const float*)d_in[8];
    const float* bs2     = (const float*)d_in[9];
    const float* fir     = (const float*)d_in[10];
    const int*   starts  = (const int*)d_in[11];
    const int*   lengths = (const int*)d_in[12];

    const int N  = in_sizes[0];
    const int Dn = out_size;
    float* out = (float*)d_out;

    int n_tiles = (Dn + TO - 1) / TO;
    synth_fused_k<<<n_tiles, 128, 0, stream>>>(
        freq, velo, w1, b1, w2, b2, ws1, bs1, ws2, bs2,
        fir, starts, lengths, out, Dn, N);
}

// Round 16
// 143.750 us; speedup vs baseline: 1.0082x; 1.0082x over previous
//
#include <hip/hip_runtime.h>
#include <math.h>

#define LMAX  32768
#define WWIN  1024
#define KFIR  128
#define WOUT  512                // outputs per wave (two 256-output MFMA chunks)
#define TO    1024               // outputs per block (2 waves)
#define CPAD  656                // padded shift-copy length (halves); 1312 B (16B mult)
#define NMAX  1024               // max notes
#define PMAX  96                 // params chunk (LDS-resident note params)

typedef _Float16 v8h __attribute__((ext_vector_type(8)));
typedef _Float16 v4h __attribute__((ext_vector_type(4)));
typedef float    v4f __attribute__((ext_vector_type(4)));

__device__ __forceinline__ float fast_tanh(float x) {
    float e = __builtin_amdgcn_exp2f(x * 2.8853900817779268f);  // 2*log2(e)
    return fmaf(-2.0f, __builtin_amdgcn_rcpf(e + 1.0f), 1.0f);
}

// ---------------- single fused kernel ----------------
// r12 synth structure (TO=1024, 2 waves x WOUT=512, fp16 4-shift-copy staging,
// 24x mfma_f32_16x16x32_f16 FIR) + in-block param MLP.  vs r15:
//  (1) one-pair-ahead REGISTER prefetch of note params restored (r12 pipeline,
//      sourced from LDS) -- r15 dropped it and paid ~120cyc lgkmcnt per pair;
//  (2) chunk-0 param MLP runs BEFORE afrag build/zero-pad so the non-MLP wave
//      and post-MLP lanes fill the barrier window with useful work.
__global__ __launch_bounds__(128, 3) void synth_fused_k(
    const float* __restrict__ freq_g, const float* __restrict__ velo_g,
    const float* __restrict__ w1,  const float* __restrict__ b1,
    const float* __restrict__ w2,  const float* __restrict__ b2,
    const float* __restrict__ ws1, const float* __restrict__ bs1,
    const float* __restrict__ ws2, const float* __restrict__ bs2,
    const float* __restrict__ fir,
    const int* __restrict__ starts, const int* __restrict__ lengths,
    float* __restrict__ out, int Dn, int N)
{
    __shared__ __align__(16) _Float16 segc[2][4][CPAD];   // 10.5 KB
    __shared__ float fir_s[KFIR];
    __shared__ unsigned short note_list[NMAX];
    __shared__ int note_cnt;
    __shared__ float s_w1[32], s_b1[32], s_w2[64], s_b2[2];
    __shared__ float s_ws1[256], s_bs1[64], s_ws2[512], s_bs2[8];
    __shared__ int   stl[PMAX], oll[PMAX];
    __shared__ float fl[PMAX];
    __shared__ __align__(16) float ampsl[PMAX][8];

    const int tid  = threadIdx.x;
    const int wid  = tid >> 6;
    const int lane = tid & 63;
    const int m    = lane & 15;
    const int quad = lane >> 4;
    const int o0   = blockIdx.x * TO;
    const int o_end = min(o0 + TO, Dn);
    const int ow   = o0 + wid * WOUT;         // this wave's first output

    // ---- stage FIR taps + MLP weights ----
    fir_s[tid] = fir[tid];
    if (tid < 32) { s_w1[tid] = w1[tid]; s_b1[tid] = b1[tid]; }
    if (tid < 64) { s_w2[tid] = w2[tid]; s_bs1[tid] = bs1[tid]; }
    if (tid < 2)  s_b2[tid] = b2[tid];
    if (tid < 8)  s_bs2[tid] = bs2[tid];
    s_ws1[tid] = ws1[tid];       s_ws1[tid + 128] = ws1[tid + 128];
    s_ws2[tid] = ws2[tid];       s_ws2[tid + 128] = ws2[tid + 128];
    s_ws2[tid + 256] = ws2[tid + 256]; s_ws2[tid + 384] = ws2[tid + 384];
    if (tid == 0) note_cnt = 0;
    __syncthreads();

    // ---- build note list for this tile ----
    for (int j = tid; j < N; j += 128) {
        int st = starts[j];
        int len = lengths[j];
        int ol = min(st + len, Dn) - st;
        ol = max(0, min(ol, LMAX));
        if (st < o_end && st + ol > o0) {
            int p = atomicAdd(&note_cnt, 1);
            note_list[p] = (unsigned short)j;
        }
    }
    __syncthreads();
    const int K = note_cnt;

    // ---- chunk-0 param MLP (divergent; wave without work overlaps below) ----
    const int kn0 = min(K, PMAX);
    if (tid < kn0) {
        const int nid = (int)note_list[tid];
        int st  = starts[nid];
        int len = lengths[nid];
        int ol  = min(st + len, Dn) - st;
        ol = max(0, min(ol, LMAX));
        stl[tid] = st;
        oll[tid] = ol;
        float v = velo_g[nid] * (1.0f / 127.0f);
        float f = freq_g[nid];
        fl[tid] = f;
        float nt = (float)st / (float)Dn;
        float lat0 = s_b2[0], lat1 = s_b2[1];
        #pragma unroll
        for (int j = 0; j < 32; ++j) {
            float h = fmaxf(fmaf(nt, s_w1[j], s_b1[j]), 0.0f);
            lat0 = fmaf(h, s_w2[j * 2 + 0], lat0);
            lat1 = fmaf(h, s_w2[j * 2 + 1], lat1);
        }
        float acc[8];
        #pragma unroll
        for (int h = 0; h < 8; ++h) acc[h] = s_bs2[h];
        #pragma unroll
        for (int j = 0; j < 64; ++j) {
            float a = s_bs1[j];
            a = fmaf(f,    s_ws1[0 * 64 + j], a);
            a = fmaf(v,    s_ws1[1 * 64 + j], a);
            a = fmaf(lat0, s_ws1[2 * 64 + j], a);
            a = fmaf(lat1, s_ws1[3 * 64 + j], a);
            a = fmaxf(a, 0.0f);
            #pragma unroll
            for (int h = 0; h < 8; ++h)
                acc[h] = fmaf(a, s_ws2[j * 8 + h], acc[h]);
        }
        #pragma unroll
        for (int h = 0; h < 8; ++h) {
            float a = acc[h];
            float sp = fmaxf(a, 0.0f) + log1pf(expf(-fabsf(a)));
            ampsl[tid][h] = sp * v;           // velocity folded in
        }
    }

    // ---- A fragments + zero-pad (independent of params; overlaps MLP) ----
    v8h afrag[12];
    #pragma unroll
    for (int t = 0; t < 12; ++t) {
        v8h af;
        #pragma unroll
        for (int j = 0; j < 8; ++j) {
            int idx = 32 * t + 8 * quad + j - 16 * m;
            float fv = (idx >= 0 && idx < KFIR) ? fir_s[idx] : 0.0f;
            af[j] = (_Float16)fv;
        }
        afrag[t] = af;
    }
    for (int z = lane; z < 4 * 20; z += 64) {
        int S = z / 20, off = z % 20;
        segc[wid][S][636 + off] = (_Float16)0.0f;
    }
    __syncthreads();                          // chunk-0 params ready

    // per-lane B read base: copy c = m&3, in-copy half index (m&~3)+8*quad (8B aligned)
    const _Float16* __restrict__ bbase = &segc[wid][m & 3][(m & ~3) + 8 * quad];

    float accA0 = 0.f, accA1 = 0.f, accA2 = 0.f, accA3 = 0.f;
    float accB0 = 0.f, accB1 = 0.f, accB2 = 0.f, accB3 = 0.f;

    const double inv2pi = 0.15915494309189535;

    for (int c = 0; c < K; c += PMAX) {
        const int kn = min(K - c, PMAX);

        if (c > 0) {                          // rare: >96 overlapping notes
            __syncthreads();
            if (tid < kn) {
                const int nid = (int)note_list[c + tid];
                int st  = starts[nid];
                int len = lengths[nid];
                int ol  = min(st + len, Dn) - st;
                ol = max(0, min(ol, LMAX));
                stl[tid] = st;
                oll[tid] = ol;
                float v = velo_g[nid] * (1.0f / 127.0f);
                float f = freq_g[nid];
                fl[tid] = f;
                float nt = (float)st / (float)Dn;
                float lat0 = s_b2[0], lat1 = s_b2[1];
                #pragma unroll
                for (int j = 0; j < 32; ++j) {
                    float h = fmaxf(fmaf(nt, s_w1[j], s_b1[j]), 0.0f);
                    lat0 = fmaf(h, s_w2[j * 2 + 0], lat0);
                    lat1 = fmaf(h, s_w2[j * 2 + 1], lat1);
                }
                float acc[8];
                #pragma unroll
                for (int h = 0; h < 8; ++h) acc[h] = s_bs2[h];
                #pragma unroll
                for (int j = 0; j < 64; ++j) {
                    float a = s_bs1[j];
                    a = fmaf(f,    s_ws1[0 * 64 + j], a);
                    a = fmaf(v,    s_ws1[1 * 64 + j], a);
                    a = fmaf(lat0, s_ws1[2 * 64 + j], a);
                    a = fmaf(lat1, s_ws1[3 * 64 + j], a);
                    a = fmaxf(a, 0.0f);
                    #pragma unroll
                    for (int h = 0; h < 8; ++h)
                        acc[h] = fmaf(a, s_ws2[j * 8 + h], acc[h]);
                }
                #pragma unroll
                for (int h = 0; h < 8; ++h) {
                    float a = acc[h];
                    float sp = fmaxf(a, 0.0f) + log1pf(expf(-fabsf(a)));
                    ampsl[tid][h] = sp * v;
                }
            }
            __syncthreads();
        }

        // ---- prefetch pair 0's params (register pipeline, r12-style) ----
        int stN = 0, olN = 0; float fN = 0.f;
        float4 amN0 = {}, amN1 = {};
        if (kn > 0) {
            stN = stl[0]; olN = oll[0]; fN = fl[0];
            amN0 = *(const float4*)&ampsl[0][0];
            amN1 = *(const float4*)&ampsl[0][4];
        }

        for (int kk = 0; kk < kn; ++kk) {
            const int st = stN, ol = olN;
            const float f = fN;
            const float4 am0 = amN0, am1 = amN1;
            if (kk + 1 < kn) {                // issue next pair's LDS loads now
                stN = stl[kk + 1]; olN = oll[kk + 1]; fN = fl[kk + 1];
                amN0 = *(const float4*)&ampsl[kk + 1][0];
                amN1 = *(const float4*)&ampsl[kk + 1][4];
            }

            const int base = ow - st;         // note-local index of wave's first output
            if (base >= ol || base + WOUT <= 0) continue;   // wave-uniform skip

            const float A0 = am0.x, A1 = am0.y, A2 = am0.z, A3 = am0.w;
            const float A4 = am1.x, A5 = am1.y, A6 = am1.z, A7 = am1.w;
            const double fd = (double)f;

            const int tseed = base - 127 + lane;
            double rev0 = fd * (double)tseed * inv2pi;
            float r0 = (float)(rev0 - floor(rev0));
            float s = __builtin_amdgcn_sinf(r0);
            float cc = __builtin_amdgcn_cosf(r0);
            double d64 = fd * 64.0 * inv2pi;
            float r64 = (float)(d64 - floor(d64));
            const float sd = __builtin_amdgcn_sinf(r64);
            const float cd = __builtin_amdgcn_cosf(r64);
            const int wbase = ol - WWIN;

            const bool interior = (base >= 127) && (base + 513 <= wbase);

            if (interior) {
                #pragma unroll
                for (int i = 0; i < 10; ++i) {
                    float tc = cc + cc;
                    float sA = s;
                    float sum = A0 * sA;
                    float sB = tc * sA;              sum = fmaf(A1, sB, sum);
                    float sC = fmaf(tc, sB, -sA);    sum = fmaf(A2, sC, sum);
                    float sD = fmaf(tc, sC, -sB);    sum = fmaf(A3, sD, sum);
                    float sE = fmaf(tc, sD, -sC);    sum = fmaf(A4, sE, sum);
                    float sF = fmaf(tc, sE, -sD);    sum = fmaf(A5, sF, sum);
                    float sG = fmaf(tc, sF, -sE);    sum = fmaf(A6, sG, sum);
                    float sH = fmaf(tc, sG, -sF);    sum = fmaf(A7, sH, sum);
                    _Float16 h = (_Float16)sum;
                    const int x = lane + 64 * i;
                    if (i == 0) {
                        #pragma unroll
                        for (int S = 0; S < 4; ++S)
                            if (x >= S) segc[wid][S][x - S] = h;
                    } else {
                        #pragma unroll
                        for (int S = 0; S < 4; ++S)
                            segc[wid][S][x - S] = h;
                    }
                    float ns = fmaf(s, cd, cc * sd);
                    float nc = fmaf(cc, cd, -(s * sd));
                    s = ns; cc = nc;
                }
            } else {
                #pragma unroll
                for (int i = 0; i < 10; ++i) {
                    int t = tseed + 64 * i;
                    float val = 0.0f;
                    if (t >= 0 && t < ol) {
                        float tc = cc + cc;
                        float sA = s;
                        float sum = A0 * sA;
                        float sB = tc * sA;              sum = fmaf(A1, sB, sum);
                        float sC = fmaf(tc, sB, -sA);    sum = fmaf(A2, sC, sum);
                        float sD = fmaf(tc, sC, -sB);    sum = fmaf(A3, sD, sum);
                        float sE = fmaf(tc, sD, -sC);    sum = fmaf(A4, sE, sum);
                        float sF = fmaf(tc, sE, -sD);    sum = fmaf(A5, sF, sum);
                        float sG = fmaf(tc, sF, -sE);    sum = fmaf(A6, sG, sum);
                        float sH = fmaf(tc, sG, -sF);    sum = fmaf(A7, sH, sum);
                        int wpos = t - wbase;
                        float factor = 1.0f;
                        if (wpos >= 0)
                            factor = 0.5f - 0.5f * __builtin_amdgcn_cosf((float)wpos * (1.0f / WWIN));
                        val = sum * factor;
                    }
                    _Float16 h = (_Float16)val;
                    const int x = lane + 64 * i;
                    if (i == 0) {
                        #pragma unroll
                        for (int S = 0; S < 4; ++S)
                            if (x >= S) segc[wid][S][x - S] = h;
                    } else {
                        #pragma unroll
                        for (int S = 0; S < 4; ++S)
                            segc[wid][S][x - S] = h;
                    }
                    float ns = fmaf(s, cd, cc * sd);
                    float nc = fmaf(cc, cd, -(s * sd));
                    s = ns; cc = nc;
                }
            }

            // ---- FIR as 24x MFMA, 4 independent accumulator chains ----
            v4f CA0 = {0.f, 0.f, 0.f, 0.f};
            v4f CA1 = {0.f, 0.f, 0.f, 0.f};
            v4f CB0 = {0.f, 0.f, 0.f, 0.f};
            v4f CB1 = {0.f, 0.f, 0.f, 0.f};
            #pragma unroll
            for (int t = 0; t < 6; ++t) {
                v4h lo = *(const v4h*)(bbase + 32 * t);
                v4h hi = *(const v4h*)(bbase + 32 * t + 4);
                v8h bf = __builtin_shufflevector(lo, hi, 0, 1, 2, 3, 4, 5, 6, 7);
                CA0 = __builtin_amdgcn_mfma_f32_16x16x32_f16(afrag[t], bf, CA0, 0, 0, 0);
                v4h lo2 = *(const v4h*)(bbase + 256 + 32 * t);
                v4h hi2 = *(const v4h*)(bbase + 256 + 32 * t + 4);
                v8h bf2 = __builtin_shufflevector(lo2, hi2, 0, 1, 2, 3, 4, 5, 6, 7);
                CB0 = __builtin_amdgcn_mfma_f32_16x16x32_f16(afrag[t], bf2, CB0, 0, 0, 0);
            }
            #pragma unroll
            for (int t = 6; t < 12; ++t) {
                v4h lo = *(const v4h*)(bbase + 32 * t);
                v4h hi = *(const v4h*)(bbase + 32 * t + 4);
                v8h bf = __builtin_shufflevector(lo, hi, 0, 1, 2, 3, 4, 5, 6, 7);
                CA1 = __builtin_amdgcn_mfma_f32_16x16x32_f16(afrag[t], bf, CA1, 0, 0, 0);
                v4h lo2 = *(const v4h*)(bbase + 256 + 32 * t);
                v4h hi2 = *(const v4h*)(bbase + 256 + 32 * t + 4);
                v8h bf2 = __builtin_shufflevector(lo2, hi2, 0, 1, 2, 3, 4, 5, 6, 7);
                CB1 = __builtin_amdgcn_mfma_f32_16x16x32_f16(afrag[t], bf2, CB1, 0, 0, 0);
            }

            // ---- tanh + masked accumulate ----
            {
                const int tb = base + 64 * quad + m;
                float y;
                y = CA0[0] + CA1[0]; if (tb +   0 >= 0 && tb +   0 < ol) accA0 += fast_tanh(y);
                y = CA0[1] + CA1[1]; if (tb +  16 >= 0 && tb +  16 < ol) accA1 += fast_tanh(y);
                y = CA0[2] + CA1[2]; if (tb +  32 >= 0 && tb +  32 < ol) accA2 += fast_tanh(y);
                y = CA0[3] + CA1[3]; if (tb +  48 >= 0 && tb +  48 < ol) accA3 += fast_tanh(y);
                y = CB0[0] + CB1[0]; if (tb + 256 >= 0 && tb + 256 < ol) accB0 += fast_tanh(y);
                y = CB0[1] + CB1[1]; if (tb + 272 >= 0 && tb + 272 < ol) accB1 += fast_tanh(y);
                y = CB0[2] + CB1[2]; if (tb + 288 >= 0 && tb + 288 < ol) accB2 += fast_tanh(y);
                y = CB0[3] + CB1[3]; if (tb + 304 >= 0 && tb + 304 < ol) accB3 += fast_tanh(y);
            }
        }
    }

    // ---- stores (C/D layout: 16-lane coalesced runs) ----
    const int ob = ow + 64 * quad + m;
    if (ob +   0 < Dn) out[ob +   0] = accA0;
    if (ob +  16 < Dn) out[ob +  16] = accA1;
    if (ob +  32 < Dn) out[ob +  32] = accA2;
    if (ob +  48 < Dn) out[ob +  48] = accA3;
    if (ob + 256 < Dn) out[ob + 256] = accB0;
    if (ob + 272 < Dn) out[ob + 272] = accB1;
    if (ob + 288 < Dn) out[ob + 288] = accB2;
    if (ob + 304 < Dn) out[ob + 304] = accB3;
}

// ---------------- launcher (single dispatch) ----------------
extern "C" void kernel_launch(void* const* d_in, const int* in_sizes, int n_in,
                              void* d_out, int out_size, void* d_ws, size_t ws_size,
                              hipStream_t stream) {
    const float* freq    = (const float*)d_in[0];
    const float* velo    = (const float*)d_in[1];
    const float* w1      = (const float*)d_in[2];
    const float* b1      = (const float*)d_in[3];
    const float* w2      = (const float*)d_in[4];
    const float* b2      = (const float*)d_in[5];
    const float* ws1     = (const float*)d_in[6];
    const float* bs1     = (const float*)d_in[7];
    const float* ws2     = (const float*)d_in[8];
    const float* bs2     = (const float*)d_in[9];
    const float* fir     = (const float*)d_in[10];
    const int*   starts  = (const int*)d_in[11];
    const int*   lengths = (const int*)d_in[12];

    const int N  = in_sizes[0];
    const int Dn = out_size;
    float* out = (float*)d_out;

    int n_tiles = (Dn + TO - 1) / TO;
    synth_fused_k<<<n_tiles, 128, 0, stream>>>(
        freq, velo, w1, b1, w2, b2, ws1, bs1, ws2, bs2,
        fir, starts, lengths, out, Dn, N);
}